// Round 1
// baseline (1609.609 us; speedup 1.0000x reference)
//
#include <hip/hip_runtime.h>

#define NIN 64
#define NOUT 32
#define TBITS 21                 // 128^3 lattice
#define TSIZE (1 << TBITS)

// ---- fill direct table with -1 (ws is poisoned 0xAA every call) ----
__global__ void init_table4(int4* __restrict__ table, int n4) {
    int i = blockIdx.x * blockDim.x + threadIdx.x;
    if (i < n4) table[i] = make_int4(-1, -1, -1, -1);
}

// ---- scatter input point indices into the dense stride-2 lattice table ----
__global__ void build_table(const int* __restrict__ coords, int np,
                            int* __restrict__ table) {
    int i = blockIdx.x * blockDim.x + threadIdx.x;
    if (i >= np) return;
    int x = coords[i * 4 + 1];
    int y = coords[i * 4 + 2];
    int z = coords[i * 4 + 3];
    int lin = (x >> 1) | ((y >> 1) << 7) | ((z >> 1) << 14);
    table[lin] = i;
}

// ---- main: one guide per 32 lanes (lane = output channel) ----
__launch_bounds__(256)
__global__ void gen_conv(const float* __restrict__ feats,     // [Np,64]
                         const float* __restrict__ weights,   // [27,64,32]
                         const float* __restrict__ bias,      // [32]
                         const int*  __restrict__ guide,      // [Ng,4]
                         const int*  __restrict__ table,      // [2^21]
                         float* __restrict__ out, int ng) {
    int tid = blockIdx.x * blockDim.x + threadIdx.x;
    int g  = tid >> 5;
    int ch = tid & 31;
    if (g >= ng) return;

    int gx = guide[g * 4 + 1];
    int gy = guide[g * 4 + 2];
    int gz = guide[g * 4 + 3];

    float acc = 0.f;
    bool exists = false;

    #pragma unroll
    for (int ox = -1; ox <= 1; ++ox) {
        #pragma unroll
        for (int oy = -1; oy <= 1; ++oy) {
            #pragma unroll
            for (int oz = -1; oz <= 1; ++oz) {
                int px = gx - ox, py = gy - oy, pz = gz - oz;
                // candidate iff p is even per-component and inside [0,256)
                bool cand = (((px | py | pz) & 1) == 0) &
                            ((unsigned)px < 256u) &
                            ((unsigned)py < 256u) &
                            ((unsigned)pz < 256u);
                if (cand) {
                    int lin = (px >> 1) | ((py >> 1) << 7) | ((pz >> 1) << 14);
                    int idx = table[lin];
                    if (idx >= 0) {
                        exists = true;
                        int oi = (ox + 1) * 9 + (oy + 1) * 3 + (oz + 1);
                        const float4* f4 = (const float4*)(feats + (size_t)idx * NIN);
                        const float* w = weights + oi * (NIN * NOUT) + ch;
                        #pragma unroll
                        for (int k4 = 0; k4 < NIN / 4; ++k4) {
                            float4 f = f4[k4];
                            acc = fmaf(f.x, w[(k4 * 4 + 0) * NOUT], acc);
                            acc = fmaf(f.y, w[(k4 * 4 + 1) * NOUT], acc);
                            acc = fmaf(f.z, w[(k4 * 4 + 2) * NOUT], acc);
                            acc = fmaf(f.w, w[(k4 * 4 + 3) * NOUT], acc);
                        }
                    }
                }
            }
        }
    }

    out[(size_t)g * NOUT + ch] = exists ? (acc + bias[ch]) : 0.f;
}

extern "C" void kernel_launch(void* const* d_in, const int* in_sizes, int n_in,
                              void* d_out, int out_size, void* d_ws, size_t ws_size,
                              hipStream_t stream) {
    const float* feats   = (const float*)d_in[0];
    const float* weights = (const float*)d_in[1];
    const float* bias    = (const float*)d_in[2];
    const int*   coords  = (const int*)d_in[3];
    const int*   guide   = (const int*)d_in[4];
    float* out = (float*)d_out;

    int np = in_sizes[3] / 4;
    int ng = in_sizes[4] / 4;

    int* table = (int*)d_ws;   // 2^21 * 4 B = 8 MB

    hipLaunchKernelGGL(init_table4, dim3(TSIZE / 4 / 256), dim3(256), 0, stream,
                       (int4*)table, TSIZE / 4);
    hipLaunchKernelGGL(build_table, dim3((np + 255) / 256), dim3(256), 0, stream,
                       coords, np, table);

    long long threads = (long long)ng * 32;
    int blocks = (int)((threads + 255) / 256);
    hipLaunchKernelGGL(gen_conv, dim3(blocks), dim3(256), 0, stream,
                       feats, weights, bias, guide, table, out, ng);
}

// Round 2
// 381.063 us; speedup vs baseline: 4.2240x; 4.2240x over previous
//
#include <hip/hip_runtime.h>

#define NIN 64
#define NOUT 32
#define TBITS 21                 // 128^3 stride-2 lattice
#define TSIZE (1 << TBITS)

// ---- fill direct table with -1 (ws is poisoned 0xAA every call) ----
__global__ void init_table4(int4* __restrict__ table, int n4) {
    int i = blockIdx.x * blockDim.x + threadIdx.x;
    if (i < n4) table[i] = make_int4(-1, -1, -1, -1);
}

// ---- scatter input point indices into the dense stride-2 lattice table ----
__global__ void build_table(const int* __restrict__ coords, int np,
                            int* __restrict__ table) {
    int i = blockIdx.x * blockDim.x + threadIdx.x;
    if (i >= np) return;
    int x = coords[i * 4 + 1];
    int y = coords[i * 4 + 2];
    int z = coords[i * 4 + 3];
    int lin = (x >> 1) | ((y >> 1) << 7) | ((z >> 1) << 14);
    table[lin] = i;
}

// ---- main: 8 lanes per guide. Lane sub=0..7 enumerates the <=8
// parity-admissible kernel offsets (one table probe per lane, issued as a
// single wave-wide load). Hit loop driven by ballot mask; each lane then
// accumulates 4 output channels (float4). ----
__launch_bounds__(256)
__global__ void gen_conv(const float* __restrict__ feats,     // [Np,64]
                         const float* __restrict__ weights,   // [27,64,32]
                         const float* __restrict__ bias,      // [32]
                         const int*  __restrict__ guide,      // [Ng,4]
                         const int*  __restrict__ table,      // [2^21]
                         float* __restrict__ out, int ng) {
    int tid  = blockIdx.x * blockDim.x + threadIdx.x;
    int g    = tid >> 3;              // guide index (8 lanes per guide)
    int sub  = threadIdx.x & 7;       // combo id / channel-quad id
    int lane = threadIdx.x & 63;
    int grp  = lane >> 3;             // group within wave (0..7)
    if (g >= ng) return;

    int4 q = ((const int4*)guide)[g];
    int qx = q.y, qy = q.z, qz = q.w;

    // parity: odd component -> off in {-1,+1} (chosen by bit); even -> off=0
    int ex = qx & 1, ey = qy & 1, ez = qz & 1;
    int exmask = ex | (ey << 1) | (ez << 2);
    int b0 = sub & 1, b1 = (sub >> 1) & 1, b2 = (sub >> 2) & 1;
    int offx = ex ? (b0 ? 1 : -1) : 0;
    int offy = ey ? (b1 ? 1 : -1) : 0;
    int offz = ez ? (b2 ? 1 : -1) : 0;
    int px = qx - offx, py = qy - offy, pz = qz - offz;
    // dedupe (bit set on even component -> duplicate combo) + bounds
    bool valid = ((sub & ~exmask & 7) == 0) &
                 ((unsigned)px < 256u) & ((unsigned)py < 256u) & ((unsigned)pz < 256u);
    int lin = (px >> 1) | ((py >> 1) << 7) | ((pz >> 1) << 14);
    // unconditional probe (safe address when invalid) -> one vmem inst/wave
    int idx = table[valid ? lin : 0];
    idx = valid ? idx : -1;
    int oi = (offx + 1) * 9 + (offy + 1) * 3 + (offz + 1);

    unsigned long long m = __ballot(idx >= 0);
    unsigned gm = (unsigned)((m >> (grp * 8)) & 0xffull);
    bool exists = (gm != 0);

    float4 acc = make_float4(0.f, 0.f, 0.f, 0.f);

    while (gm) {
        int b = __builtin_ctz(gm);
        gm &= gm - 1;
        int src  = (grp << 3) | b;
        int hidx = __shfl(idx, src, 64);
        int hoi  = __shfl(oi,  src, 64);

        const float4* f4 = (const float4*)(feats + (size_t)hidx * NIN);
        const float4* w4 = (const float4*)(weights + (size_t)hoi * (NIN * NOUT)) + sub;
        #pragma unroll 4
        for (int k4 = 0; k4 < NIN / 4; ++k4) {
            float4 f  = f4[k4];
            float4 wa = w4[(k4 * 4 + 0) * (NOUT / 4)];
            float4 wb = w4[(k4 * 4 + 1) * (NOUT / 4)];
            float4 wc = w4[(k4 * 4 + 2) * (NOUT / 4)];
            float4 wd = w4[(k4 * 4 + 3) * (NOUT / 4)];
            acc.x = fmaf(f.x, wa.x, acc.x); acc.y = fmaf(f.x, wa.y, acc.y);
            acc.z = fmaf(f.x, wa.z, acc.z); acc.w = fmaf(f.x, wa.w, acc.w);
            acc.x = fmaf(f.y, wb.x, acc.x); acc.y = fmaf(f.y, wb.y, acc.y);
            acc.z = fmaf(f.y, wb.z, acc.z); acc.w = fmaf(f.y, wb.w, acc.w);
            acc.x = fmaf(f.z, wc.x, acc.x); acc.y = fmaf(f.z, wc.y, acc.y);
            acc.z = fmaf(f.z, wc.z, acc.z); acc.w = fmaf(f.z, wc.w, acc.w);
            acc.x = fmaf(f.w, wd.x, acc.x); acc.y = fmaf(f.w, wd.y, acc.y);
            acc.z = fmaf(f.w, wd.z, acc.z); acc.w = fmaf(f.w, wd.w, acc.w);
        }
    }

    float4 r = make_float4(0.f, 0.f, 0.f, 0.f);
    if (exists) {
        float4 bv = ((const float4*)bias)[sub];
        r.x = acc.x + bv.x; r.y = acc.y + bv.y;
        r.z = acc.z + bv.z; r.w = acc.w + bv.w;
    }
    ((float4*)out)[(size_t)g * (NOUT / 4) + sub] = r;
}

extern "C" void kernel_launch(void* const* d_in, const int* in_sizes, int n_in,
                              void* d_out, int out_size, void* d_ws, size_t ws_size,
                              hipStream_t stream) {
    const float* feats   = (const float*)d_in[0];
    const float* weights = (const float*)d_in[1];
    const float* bias    = (const float*)d_in[2];
    const int*   coords  = (const int*)d_in[3];
    const int*   guide   = (const int*)d_in[4];
    float* out = (float*)d_out;

    int np = in_sizes[3] / 4;
    int ng = in_sizes[4] / 4;

    int* table = (int*)d_ws;   // 2^21 * 4 B = 8 MB

    hipLaunchKernelGGL(init_table4, dim3(TSIZE / 4 / 256), dim3(256), 0, stream,
                       (int4*)table, TSIZE / 4);
    hipLaunchKernelGGL(build_table, dim3((np + 255) / 256), dim3(256), 0, stream,
                       coords, np, table);

    long long threads = (long long)ng * 8;
    int blocks = (int)((threads + 255) / 256);
    hipLaunchKernelGGL(gen_conv, dim3(blocks), dim3(256), 0, stream,
                       feats, weights, bias, guide, table, out, ng);
}